// Round 1
// baseline (2301.925 us; speedup 1.0000x reference)
//
#include <hip/hip_runtime.h>
#include <hip/hip_bf16.h>

// GraphSAGE 2-layer:
//   h   = relu(mean_agg(x) @ W1l + b1 + x @ W1r)
//   out = mean_agg(h) @ W2l + b2 + h @ W2r
// mean_agg(v)[n] = sum_{e: dst[e]==n} v[src[e]] / max(deg[n],1)
// Layer-2 trick: mean_agg(h) @ W2l == mean_agg(h @ W2l)  (linearity) -> scatter 64ch not 128ch.

#define TBLOCK 256

// ---- edge-index dtype detection: int32 vs int64 --------------------------
// If edge_index arrived as int64 (little-endian, values < 2^31), every odd
// int32 word is a zero high-word. Random int32 indices make that impossible.
__global__ void detect_k(const int* __restrict__ edges, int* __restrict__ flag) {
    int tid = threadIdx.x;
    int bad = 0;
    for (int i = tid; i < 2048; i += TBLOCK)
        if (edges[2 * i + 1] != 0) bad = 1;
    unsigned long long b = __ballot(bad);
    __shared__ int sbad[4];
    int w = tid >> 6;
    if ((tid & 63) == 0) sbad[w] = (b != 0) ? 1 : 0;
    __syncthreads();
    if (tid == 0) flag[0] = (sbad[0] | sbad[1] | sbad[2] | sbad[3]) ? 0 : 1;
}

__device__ __forceinline__ int load_src(const int* e, long long i, int E, int is64) {
    return is64 ? e[2 * i] : e[i];
}
__device__ __forceinline__ int load_dst(const int* e, long long i, int E, int is64) {
    return is64 ? e[2 * (long long)E + 2 * i] : e[(long long)E + i];
}

// ---- degree ---------------------------------------------------------------
__global__ __launch_bounds__(TBLOCK) void deg_k(const int* __restrict__ edges, int E,
                                                const int* __restrict__ flag,
                                                float* __restrict__ deg) {
    int e = blockIdx.x * TBLOCK + threadIdx.x;
    if (e >= E) return;
    int is64 = *flag;
    int d = load_dst(edges, e, E, is64);
    unsafeAtomicAdd(&deg[d], 1.0f);
}

__global__ __launch_bounds__(TBLOCK) void invdeg_k(float* __restrict__ deg, int N) {
    int i = blockIdx.x * TBLOCK + threadIdx.x;
    if (i < N) deg[i] = 1.0f / fmaxf(deg[i], 1.0f);
}

// ---- scatter-add of C-wide rows: agg[dst[e]] += feat[src[e]] --------------
template <int C>
__global__ __launch_bounds__(TBLOCK) void scatter_k(const float* __restrict__ feat,
                                                    const int* __restrict__ edges, int E,
                                                    const int* __restrict__ flag,
                                                    float* __restrict__ agg) {
    constexpr int L = C / 4;                 // threads per edge (float4 each)
    int t = blockIdx.x * TBLOCK + threadIdx.x;
    int e = t / L;
    if (e >= E) return;
    int c = (t % L) * 4;
    int is64 = *flag;
    int s = load_src(edges, e, E, is64);
    int d = load_dst(edges, e, E, is64);
    float4 v = *(const float4*)(feat + (size_t)s * C + c);
    float* o = agg + (size_t)d * C + c;
    unsafeAtomicAdd(o + 0, v.x);
    unsafeAtomicAdd(o + 1, v.y);
    unsafeAtomicAdd(o + 2, v.z);
    unsafeAtomicAdd(o + 3, v.w);
}

// ---- dense transform ------------------------------------------------------
// Y[n, c] = relu?( (A_SCALE? invdeg[n]:1) * (A[n,:] @ W[:,c])
//                + (HAS_BASE? base[n,c]  * (BASE_SCALE? invdeg[n]:1) : 0)
//                + (HAS_BIAS? bias[c] : 0) )
// Weights (IN x OUT fp32, 32/64 KB) fully resident in LDS. Each thread owns a
// 4-node x 4-channel register tile -> one ds_read_b128 of W feeds 16 FMAs.
template <int OUT, bool A_SCALE, bool HAS_BASE, bool BASE_SCALE, bool HAS_BIAS, bool RELU>
__global__ __launch_bounds__(TBLOCK) void transform_k(const float* __restrict__ A,
                                                      const float* __restrict__ W,
                                                      const float* __restrict__ base,
                                                      const float* __restrict__ bias,
                                                      const float* __restrict__ invdeg,
                                                      float* __restrict__ Y, int N) {
    constexpr int IN = 128;
    constexpr int L = OUT / 4;               // channel-groups per node row
    constexpr int SUBS = TBLOCK / L;         // node groups per block
    constexpr int TILE = SUBS * 4;           // nodes per block-iteration
    __shared__ float sW[IN * OUT];           // 64 KB (OUT=128) / 32 KB (OUT=64)
    for (int i = threadIdx.x * 4; i < IN * OUT; i += TBLOCK * 4)
        *(float4*)&sW[i] = *(const float4*)&W[i];
    __syncthreads();

    const int lc = threadIdx.x % L;
    const int sub = threadIdx.x / L;
    const int c = lc * 4;

    for (int nt = blockIdx.x * TILE; nt < N; nt += gridDim.x * TILE) {
        int n[4];
        const float* ap[4];
#pragma unroll
        for (int u = 0; u < 4; u++) {
            n[u] = nt + sub * 4 + u;
            int nc = n[u] < N ? n[u] : N - 1;
            ap[u] = A + (size_t)nc * IN;
        }
        float acc[4][4] = {};
        for (int k = 0; k < IN; k += 4) {
            float4 av[4];
#pragma unroll
            for (int u = 0; u < 4; u++) av[u] = *(const float4*)(ap[u] + k);
#pragma unroll
            for (int kk = 0; kk < 4; kk++) {
                float4 w = *(const float4*)&sW[(k + kk) * OUT + c];
#pragma unroll
                for (int u = 0; u < 4; u++) {
                    float a = (&av[u].x)[kk];
                    acc[u][0] += a * w.x;
                    acc[u][1] += a * w.y;
                    acc[u][2] += a * w.z;
                    acc[u][3] += a * w.w;
                }
            }
        }
#pragma unroll
        for (int u = 0; u < 4; u++) {
            if (n[u] < N) {
                float s = A_SCALE ? invdeg[n[u]] : 1.0f;
                float4 r;
                r.x = acc[u][0] * s;
                r.y = acc[u][1] * s;
                r.z = acc[u][2] * s;
                r.w = acc[u][3] * s;
                if (HAS_BASE) {
                    float bs = BASE_SCALE ? invdeg[n[u]] : 1.0f;
                    float4 bv = *(const float4*)(base + (size_t)n[u] * OUT + c);
                    r.x += bv.x * bs;
                    r.y += bv.y * bs;
                    r.z += bv.z * bs;
                    r.w += bv.w * bs;
                }
                if (HAS_BIAS) {
                    float4 bb = *(const float4*)(bias + c);
                    r.x += bb.x;
                    r.y += bb.y;
                    r.z += bb.z;
                    r.w += bb.w;
                }
                if (RELU) {
                    r.x = fmaxf(r.x, 0.f);
                    r.y = fmaxf(r.y, 0.f);
                    r.z = fmaxf(r.z, 0.f);
                    r.w = fmaxf(r.w, 0.f);
                }
                *(float4*)(Y + (size_t)n[u] * OUT + c) = r;
            }
        }
    }
}

extern "C" void kernel_launch(void* const* d_in, const int* in_sizes, int n_in,
                              void* d_out, int out_size, void* d_ws, size_t ws_size,
                              hipStream_t stream) {
    const float* x = (const float*)d_in[0];
    const int* edges = (const int*)d_in[1];
    const float* W1l = (const float*)d_in[2];
    const float* b1 = (const float*)d_in[3];
    const float* W1r = (const float*)d_in[4];
    const float* W2l = (const float*)d_in[5];
    const float* b2 = (const float*)d_in[6];
    const float* W2r = (const float*)d_in[7];
    float* out = (float*)d_out;

    const int N = in_sizes[0] / 128;   // 50000
    const int E = in_sizes[1] / 2;     // 800000

    float* ws = (float*)d_ws;
    int* flag = (int*)d_ws;
    const size_t o_deg = 64;
    const size_t o_agg1 = o_deg + (size_t)((N + 63) & ~63);
    const size_t o_agg2 = o_agg1 + (size_t)N * 128;
    const size_t o_h = o_agg2 + (size_t)N * 64;
    float* deg = ws + o_deg;           // becomes invdeg after invdeg_k
    float* agg1 = ws + o_agg1;         // [N,128]; reused as t2 [N,64] after layer 1
    float* agg2 = ws + o_agg2;         // [N,64]
    float* h = ws + o_h;               // [N,128]
    float* t2 = agg1;                  // reuse: agg1 dead after transform call 2

    // zero flag + deg + agg1 + agg2 in one shot (ws is poisoned 0xAA each call)
    hipMemsetAsync(d_ws, 0, o_h * sizeof(float), stream);

    detect_k<<<1, TBLOCK, 0, stream>>>(edges, flag);
    deg_k<<<(E + TBLOCK - 1) / TBLOCK, TBLOCK, 0, stream>>>(edges, E, flag, deg);
    invdeg_k<<<(N + TBLOCK - 1) / TBLOCK, TBLOCK, 0, stream>>>(deg, N);

    // layer 1: agg1 = segment_sum(x[src])
    scatter_k<128><<<(E * 32 + TBLOCK - 1) / TBLOCK, TBLOCK, 0, stream>>>(x, edges, E, flag, agg1);
    // h(tmp) = x @ W1r + b1
    transform_k<128, false, false, false, true, false>
        <<<512, TBLOCK, 0, stream>>>(x, W1r, nullptr, b1, deg, h, N);
    // h = relu(h + invdeg * (agg1 @ W1l))
    transform_k<128, true, true, false, false, true>
        <<<512, TBLOCK, 0, stream>>>(agg1, W1l, h, nullptr, deg, h, N);

    // layer 2: t2 = h @ W2l  (pre-transform so scatter is 64-wide)
    transform_k<64, false, false, false, false, false>
        <<<512, TBLOCK, 0, stream>>>(h, W2l, nullptr, nullptr, deg, t2, N);
    scatter_k<64><<<(E * 16 + TBLOCK - 1) / TBLOCK, TBLOCK, 0, stream>>>(t2, edges, E, flag, agg2);
    // out = invdeg*agg2 + b2 + h @ W2r
    transform_k<64, false, true, true, true, false>
        <<<512, TBLOCK, 0, stream>>>(h, W2r, agg2, b2, deg, out, N);
}

// Round 2
// 387.322 us; speedup vs baseline: 5.9432x; 5.9432x over previous
//
#include <hip/hip_runtime.h>
#include <hip/hip_bf16.h>

// GraphSAGE 2-layer:
//   h   = relu(mean_agg(x) @ W1l + b1 + x @ W1r)
//   out = mean_agg(h) @ W2l + b2 + h @ W2r
// mean_agg(v)[n] = sum_{e: dst[e]==n} v[src[e]] / max(deg[n],1)
// Layer-2 trick: mean_agg(h) @ W2l == mean_agg(h @ W2l)  -> aggregate 64ch not 128ch.
// R2: atomic scatter (1.35 ms, 1.6 GB fabric atomics) replaced by per-call CSR
// build + register-accumulating gather (row written exactly once).

#define TBLOCK 256
#define CHUNK 1024   // elements per scan block (256 thr x 4)

// ---- edge-index dtype detection: int32 vs int64 --------------------------
__global__ void detect_k(const int* __restrict__ edges, int* __restrict__ flag) {
    int tid = threadIdx.x;
    int bad = 0;
    for (int i = tid; i < 2048; i += TBLOCK)
        if (edges[2 * i + 1] != 0) bad = 1;
    unsigned long long b = __ballot(bad);
    __shared__ int sbad[4];
    int w = tid >> 6;
    if ((tid & 63) == 0) sbad[w] = (b != 0) ? 1 : 0;
    __syncthreads();
    if (tid == 0) flag[0] = (sbad[0] | sbad[1] | sbad[2] | sbad[3]) ? 0 : 1;
}

__device__ __forceinline__ int load_src(const int* e, long long i, int E, int is64) {
    return is64 ? e[2 * i] : e[i];
}
__device__ __forceinline__ int load_dst(const int* e, long long i, int E, int is64) {
    return is64 ? e[2 * (long long)E + 2 * i] : e[(long long)E + i];
}

// ---- int degree histogram -------------------------------------------------
__global__ __launch_bounds__(TBLOCK) void degi_k(const int* __restrict__ edges, int E,
                                                 const int* __restrict__ flag,
                                                 int* __restrict__ degi) {
    int e = blockIdx.x * TBLOCK + threadIdx.x;
    if (e >= E) return;
    int is64 = *flag;
    atomicAdd(&degi[load_dst(edges, e, E, is64)], 1);
}

// ---- 3-phase exclusive scan of degi -> offs ------------------------------
__global__ __launch_bounds__(TBLOCK) void scan1_k(const int* __restrict__ degi,
                                                  int* __restrict__ offs,
                                                  int* __restrict__ partial, int N) {
    __shared__ int s[TBLOCK];
    int base = blockIdx.x * CHUNK;
    int t = threadIdx.x;
    int v[4];
    int sum = 0;
#pragma unroll
    for (int i = 0; i < 4; i++) {
        int idx = base + t * 4 + i;
        int d = (idx < N) ? degi[idx] : 0;
        v[i] = sum;            // exclusive within thread
        sum += d;
    }
    s[t] = sum;
    __syncthreads();
    for (int off = 1; off < TBLOCK; off <<= 1) {
        int x = (t >= off) ? s[t - off] : 0;
        __syncthreads();
        s[t] += x;
        __syncthreads();
    }
    int excl = (t == 0) ? 0 : s[t - 1];
#pragma unroll
    for (int i = 0; i < 4; i++) {
        int idx = base + t * 4 + i;
        if (idx < N) offs[idx] = excl + v[i];
    }
    if (t == TBLOCK - 1) partial[blockIdx.x] = s[TBLOCK - 1];
}

__global__ void scan2_k(int* __restrict__ partial, int nb) {
    if (threadIdx.x == 0 && blockIdx.x == 0) {
        int run = 0;
        for (int b = 0; b < nb; b++) {
            int t = partial[b];
            partial[b] = run;
            run += t;
        }
    }
}

__global__ __launch_bounds__(TBLOCK) void scan3_k(int* __restrict__ offs,
                                                  const int* __restrict__ partial,
                                                  const int* __restrict__ degi,
                                                  float* __restrict__ invdeg, int N) {
    int add = partial[blockIdx.x];
    int base = blockIdx.x * CHUNK;
#pragma unroll
    for (int i = 0; i < 4; i++) {
        int idx = base + threadIdx.x * 4 + i;
        if (idx < N) {
            offs[idx] += add;
            invdeg[idx] = 1.0f / fmaxf((float)degi[idx], 1.0f);
        }
    }
}

// ---- CSR fill: csr_src[offs[dst] + k] = src -------------------------------
__global__ __launch_bounds__(TBLOCK) void fill_k(const int* __restrict__ edges, int E,
                                                 const int* __restrict__ flag,
                                                 const int* __restrict__ offs,
                                                 int* __restrict__ cursor,
                                                 int* __restrict__ csr) {
    int e = blockIdx.x * TBLOCK + threadIdx.x;
    if (e >= E) return;
    int is64 = *flag;
    int s = load_src(edges, e, E, is64);
    int d = load_dst(edges, e, E, is64);
    int pos = offs[d] + atomicAdd(&cursor[d], 1);
    csr[pos] = s;
}

// ---- gather-aggregate: out[n] (+)= invdeg[n] * sum_{e in seg(n)} feat[src] -
template <int C, bool ACCUM>
__global__ __launch_bounds__(TBLOCK) void gather_k(const float* __restrict__ feat,
                                                   const int* __restrict__ csr,
                                                   const int* __restrict__ offs,
                                                   const int* __restrict__ degi,
                                                   const float* __restrict__ invdeg,
                                                   float* __restrict__ outp, int N) {
    constexpr int G = C / 4;                 // lanes per node (float4 each)
    constexpr int NPB = TBLOCK / G;
    int n = blockIdx.x * NPB + threadIdx.x / G;
    if (n >= N) return;
    int lane = threadIdx.x % G;
    int c = lane * 4;
    int s0 = offs[n];
    int d = degi[n];
    float4 acc = {0.f, 0.f, 0.f, 0.f};
    for (int base = 0; base < d; base += G) {
        int my = (base + lane < d) ? csr[s0 + base + lane] : 0;
        int cnt = min(G, d - base);
        for (int j = 0; j < cnt; j++) {
            int sidx = __shfl(my, j, G);
            float4 v = *(const float4*)(feat + (size_t)sidx * C + c);
            acc.x += v.x;
            acc.y += v.y;
            acc.z += v.z;
            acc.w += v.w;
        }
    }
    float s = invdeg[n];
    float* o = outp + (size_t)n * C + c;
    float4 r;
    if (ACCUM) {
        float4 p = *(const float4*)o;
        r.x = p.x + acc.x * s;
        r.y = p.y + acc.y * s;
        r.z = p.z + acc.z * s;
        r.w = p.w + acc.w * s;
    } else {
        r.x = acc.x * s;
        r.y = acc.y * s;
        r.z = acc.z * s;
        r.w = acc.w * s;
    }
    *(float4*)o = r;
}

// ---- dense transform ------------------------------------------------------
// Y[n,c] = relu?( A[n,:]@W[:,c] + (HAS_BASE? base[n,c] : 0) + (HAS_BIAS? bias[c] : 0) )
// Weights fully in LDS; 4-node x 4-channel register tile per thread.
template <int OUT, bool HAS_BASE, bool HAS_BIAS, bool RELU>
__global__ __launch_bounds__(TBLOCK) void transform_k(const float* __restrict__ A,
                                                      const float* __restrict__ W,
                                                      const float* __restrict__ base,
                                                      const float* __restrict__ bias,
                                                      float* __restrict__ Y, int N) {
    constexpr int IN = 128;
    constexpr int L = OUT / 4;
    constexpr int SUBS = TBLOCK / L;
    constexpr int TILE = SUBS * 4;
    __shared__ float sW[IN * OUT];
    for (int i = threadIdx.x * 4; i < IN * OUT; i += TBLOCK * 4)
        *(float4*)&sW[i] = *(const float4*)&W[i];
    __syncthreads();

    const int lc = threadIdx.x % L;
    const int sub = threadIdx.x / L;
    const int c = lc * 4;

    for (int nt = blockIdx.x * TILE; nt < N; nt += gridDim.x * TILE) {
        int n[4];
        const float* ap[4];
#pragma unroll
        for (int u = 0; u < 4; u++) {
            n[u] = nt + sub * 4 + u;
            int nc = n[u] < N ? n[u] : N - 1;
            ap[u] = A + (size_t)nc * IN;
        }
        float acc[4][4] = {};
        for (int k = 0; k < IN; k += 4) {
            float4 av[4];
#pragma unroll
            for (int u = 0; u < 4; u++) av[u] = *(const float4*)(ap[u] + k);
#pragma unroll
            for (int kk = 0; kk < 4; kk++) {
                float4 w = *(const float4*)&sW[(k + kk) * OUT + c];
#pragma unroll
                for (int u = 0; u < 4; u++) {
                    float a = (&av[u].x)[kk];
                    acc[u][0] += a * w.x;
                    acc[u][1] += a * w.y;
                    acc[u][2] += a * w.z;
                    acc[u][3] += a * w.w;
                }
            }
        }
#pragma unroll
        for (int u = 0; u < 4; u++) {
            if (n[u] < N) {
                float4 r = {acc[u][0], acc[u][1], acc[u][2], acc[u][3]};
                if (HAS_BASE) {
                    float4 bv = *(const float4*)(base + (size_t)n[u] * OUT + c);
                    r.x += bv.x;
                    r.y += bv.y;
                    r.z += bv.z;
                    r.w += bv.w;
                }
                if (HAS_BIAS) {
                    float4 bb = *(const float4*)(bias + c);
                    r.x += bb.x;
                    r.y += bb.y;
                    r.z += bb.z;
                    r.w += bb.w;
                }
                if (RELU) {
                    r.x = fmaxf(r.x, 0.f);
                    r.y = fmaxf(r.y, 0.f);
                    r.z = fmaxf(r.z, 0.f);
                    r.w = fmaxf(r.w, 0.f);
                }
                *(float4*)(Y + (size_t)n[u] * OUT + c) = r;
            }
        }
    }
}

extern "C" void kernel_launch(void* const* d_in, const int* in_sizes, int n_in,
                              void* d_out, int out_size, void* d_ws, size_t ws_size,
                              hipStream_t stream) {
    const float* x = (const float*)d_in[0];
    const int* edges = (const int*)d_in[1];
    const float* W1l = (const float*)d_in[2];
    const float* b1 = (const float*)d_in[3];
    const float* W1r = (const float*)d_in[4];
    const float* W2l = (const float*)d_in[5];
    const float* b2 = (const float*)d_in[6];
    const float* W2r = (const float*)d_in[7];
    float* out = (float*)d_out;

    const int N = in_sizes[0] / 128;   // 50000
    const int E = in_sizes[1] / 2;     // 800000
    const int Na = (N + 63) & ~63;
    const int NB = (N + CHUNK - 1) / CHUNK;

    // workspace layout (float/int units)
    int* iws = (int*)d_ws;
    float* fws = (float*)d_ws;
    const size_t o_flag = 0;           // 64
    const size_t o_degi = 64;          // Na
    const size_t o_cur = 64 + Na;      // Na   <- memset covers [0, o_part)
    const size_t o_part = 64 + 2 * (size_t)Na;  // 64
    const size_t o_off = o_part + 64;  // Na
    const size_t o_inv = o_off + Na;   // Na
    const size_t o_csr = o_inv + Na;   // E
    const size_t o_agg1 = o_csr + E;   // N*128  (reused as t2 [N,64])
    const size_t o_h = o_agg1 + (size_t)N * 128;  // N*128

    int* flag = iws + o_flag;
    int* degi = iws + o_degi;
    int* cursor = iws + o_cur;
    int* partial = iws + o_part;
    int* offs = iws + o_off;
    float* invdeg = fws + o_inv;
    int* csr = iws + o_csr;
    float* agg1 = fws + o_agg1;
    float* t2 = agg1;
    float* h = fws + o_h;

    // zero flag + degi + cursor (ws re-poisoned 0xAA before every call)
    hipMemsetAsync(d_ws, 0, o_part * sizeof(int), stream);

    detect_k<<<1, TBLOCK, 0, stream>>>(edges, flag);
    degi_k<<<(E + TBLOCK - 1) / TBLOCK, TBLOCK, 0, stream>>>(edges, E, flag, degi);
    scan1_k<<<NB, TBLOCK, 0, stream>>>(degi, offs, partial, N);
    scan2_k<<<1, 64, 0, stream>>>(partial, NB);
    scan3_k<<<NB, TBLOCK, 0, stream>>>(offs, partial, degi, invdeg, N);
    fill_k<<<(E + TBLOCK - 1) / TBLOCK, TBLOCK, 0, stream>>>(edges, E, flag, offs, cursor, csr);

    // layer 1: agg1 = mean_agg(x)
    gather_k<128, false><<<(N * 32 + TBLOCK - 1) / TBLOCK, TBLOCK, 0, stream>>>(
        x, csr, offs, degi, invdeg, agg1, N);
    // h(tmp) = x @ W1r + b1
    transform_k<128, false, true, false>
        <<<512, TBLOCK, 0, stream>>>(x, W1r, nullptr, b1, h, N);
    // h = relu(agg1 @ W1l + h)
    transform_k<128, true, false, true>
        <<<512, TBLOCK, 0, stream>>>(agg1, W1l, h, nullptr, h, N);

    // layer 2: t2 = h @ W2l (pre-transform so aggregation is 64-wide)
    transform_k<64, false, false, false>
        <<<512, TBLOCK, 0, stream>>>(h, W2l, nullptr, nullptr, t2, N);
    // out = h @ W2r + b2
    transform_k<64, false, true, false>
        <<<512, TBLOCK, 0, stream>>>(h, W2r, nullptr, b2, out, N);
    // out += mean_agg(t2)
    gather_k<64, true><<<(N * 16 + TBLOCK - 1) / TBLOCK, TBLOCK, 0, stream>>>(
        t2, csr, offs, degi, invdeg, out, N);
}

// Round 3
// 253.447 us; speedup vs baseline: 9.0825x; 1.5282x over previous
//
#include <hip/hip_runtime.h>
#include <hip/hip_bf16.h>

// GraphSAGE 2-layer on MI355X.
//   h   = relu(mean_agg(x) @ W1l + b1 + x @ W1r)
//   out = mean_agg(h @ W2l) + b2 + h @ W2r          (aggregate AFTER transform: 64ch)
// R2: CSR-gather replaced atomic scatter (2302 -> 387 us).
// R3: bf16 feature tables for gathers (halve random-read bytes), MFMA bf16 GEMMs
//     (4 VALU transforms -> 2 matrix-core kernels), parallel scan2.

#define TBLOCK 256
#define CHUNK 1024

typedef __attribute__((ext_vector_type(8))) short short8;
typedef __attribute__((ext_vector_type(4))) float f32x4;

__device__ __forceinline__ float bf2f(ushort u) {
    union { unsigned int i; float f; } v;
    v.i = (unsigned int)u << 16;
    return v.f;
}
__device__ __forceinline__ ushort f2bf(float f) {  // RTNE
    union { float f; unsigned int u; } v;
    v.f = f;
    unsigned int r = v.u + 0x7fffu + ((v.u >> 16) & 1u);
    return (ushort)(r >> 16);
}

// ---- edge-index dtype detection: int32 vs int64 --------------------------
__global__ void detect_k(const int* __restrict__ edges, int* __restrict__ flag) {
    int tid = threadIdx.x;
    int bad = 0;
    for (int i = tid; i < 2048; i += TBLOCK)
        if (edges[2 * i + 1] != 0) bad = 1;
    unsigned long long b = __ballot(bad);
    __shared__ int sbad[4];
    int w = tid >> 6;
    if ((tid & 63) == 0) sbad[w] = (b != 0) ? 1 : 0;
    __syncthreads();
    if (tid == 0) flag[0] = (sbad[0] | sbad[1] | sbad[2] | sbad[3]) ? 0 : 1;
}

__device__ __forceinline__ int load_src(const int* e, long long i, int E, int is64) {
    return is64 ? e[2 * i] : e[i];
}
__device__ __forceinline__ int load_dst(const int* e, long long i, int E, int is64) {
    return is64 ? e[2 * (long long)E + 2 * i] : e[(long long)E + i];
}

// ---- int degree histogram -------------------------------------------------
__global__ __launch_bounds__(TBLOCK) void degi_k(const int* __restrict__ edges, int E,
                                                 const int* __restrict__ flag,
                                                 int* __restrict__ degi) {
    int e = blockIdx.x * TBLOCK + threadIdx.x;
    if (e >= E) return;
    int is64 = *flag;
    atomicAdd(&degi[load_dst(edges, e, E, is64)], 1);
}

// ---- 3-phase exclusive scan ----------------------------------------------
__global__ __launch_bounds__(TBLOCK) void scan1_k(const int* __restrict__ degi,
                                                  int* __restrict__ offs,
                                                  int* __restrict__ partial, int N) {
    __shared__ int s[TBLOCK];
    int base = blockIdx.x * CHUNK;
    int t = threadIdx.x;
    int v[4];
    int sum = 0;
#pragma unroll
    for (int i = 0; i < 4; i++) {
        int idx = base + t * 4 + i;
        int d = (idx < N) ? degi[idx] : 0;
        v[i] = sum;
        sum += d;
    }
    s[t] = sum;
    __syncthreads();
    for (int off = 1; off < TBLOCK; off <<= 1) {
        int x = (t >= off) ? s[t - off] : 0;
        __syncthreads();
        s[t] += x;
        __syncthreads();
    }
    int excl = (t == 0) ? 0 : s[t - 1];
#pragma unroll
    for (int i = 0; i < 4; i++) {
        int idx = base + t * 4 + i;
        if (idx < N) offs[idx] = excl + v[i];
    }
    if (t == TBLOCK - 1) partial[blockIdx.x] = s[TBLOCK - 1];
}

__global__ __launch_bounds__(TBLOCK) void scan2_k(int* __restrict__ partial, int nb) {
    __shared__ int s[TBLOCK];
    int t = threadIdx.x;
    int v = (t < nb) ? partial[t] : 0;
    s[t] = v;
    __syncthreads();
    for (int off = 1; off < TBLOCK; off <<= 1) {
        int x = (t >= off) ? s[t - off] : 0;
        __syncthreads();
        s[t] += x;
        __syncthreads();
    }
    if (t < nb) partial[t] = (t == 0) ? 0 : s[t - 1];
}

__global__ __launch_bounds__(TBLOCK) void scan3_k(int* __restrict__ offs,
                                                  const int* __restrict__ partial,
                                                  const int* __restrict__ degi,
                                                  float* __restrict__ invdeg, int N) {
    int add = partial[blockIdx.x];
    int base = blockIdx.x * CHUNK;
#pragma unroll
    for (int i = 0; i < 4; i++) {
        int idx = base + threadIdx.x * 4 + i;
        if (idx < N) {
            offs[idx] += add;
            invdeg[idx] = 1.0f / fmaxf((float)degi[idx], 1.0f);
        }
    }
}

// ---- CSR fill -------------------------------------------------------------
__global__ __launch_bounds__(TBLOCK) void fill_k(const int* __restrict__ edges, int E,
                                                 const int* __restrict__ flag,
                                                 const int* __restrict__ offs,
                                                 int* __restrict__ cursor,
                                                 int* __restrict__ csr) {
    int e = blockIdx.x * TBLOCK + threadIdx.x;
    if (e >= E) return;
    int is64 = *flag;
    int s = load_src(edges, e, E, is64);
    int d = load_dst(edges, e, E, is64);
    int pos = offs[d] + atomicAdd(&cursor[d], 1);
    csr[pos] = s;
}

// ---- x (fp32) -> xb (bf16), 8 elements/thread -----------------------------
__global__ __launch_bounds__(TBLOCK) void cvtx_k(const float* __restrict__ x,
                                                 ushort* __restrict__ xb, int n8) {
    int i = blockIdx.x * TBLOCK + threadIdx.x;
    if (i >= n8) return;
    const float4* p = (const float4*)x + (size_t)i * 2;
    float4 a = p[0], b = p[1];
    short8 o;
    o[0] = f2bf(a.x); o[1] = f2bf(a.y); o[2] = f2bf(a.z); o[3] = f2bf(a.w);
    o[4] = f2bf(b.x); o[5] = f2bf(b.y); o[6] = f2bf(b.z); o[7] = f2bf(b.w);
    *(short8*)(xb + (size_t)i * 8) = o;
}

// ---- weight prep: transpose+concat to bf16 chunk-major --------------------
// wc[((k>>3)*128 + n)*8 + (k&7)] = W[k][n]; B-frag load = contiguous 16B.
// wc1: K=256, Wcat1[k][n] = k<128 ? W1l[k][n] : W1r[k-128][n]      (N=128)
// wc2: K=128, Wcat2[k][n] = n<64  ? W2l[k][n] : W2r[k][n-64]       (N=128)
__global__ __launch_bounds__(TBLOCK) void cvtw_k(const float* __restrict__ W1l,
                                                 const float* __restrict__ W1r,
                                                 const float* __restrict__ W2l,
                                                 const float* __restrict__ W2r,
                                                 ushort* __restrict__ wc1,
                                                 ushort* __restrict__ wc2) {
    int i = blockIdx.x * TBLOCK + threadIdx.x;
    if (i < 32768) {
        int j = i & 7;
        int rest = i >> 3;
        int n = rest & 127;
        int k = ((rest >> 7) << 3) | j;
        float w = (k < 128) ? W1l[k * 128 + n] : W1r[(k - 128) * 128 + n];
        wc1[i] = f2bf(w);
    } else if (i < 49152) {
        int i2 = i - 32768;
        int j = i2 & 7;
        int rest = i2 >> 3;
        int n = rest & 127;
        int k = ((rest >> 7) << 3) | j;
        float w = (n < 64) ? W2l[k * 64 + n] : W2r[k * 64 + (n - 64)];
        wc2[i2] = f2bf(w);
    }
}

// ---- gather-aggregate over bf16 features ---------------------------------
// ACCUM=0: outB[n][:] = bf16(invdeg[n] * sum feat[src])      (layer 1, C=128)
// ACCUM=1: outF[n][:] += invdeg[n] * sum feat[src]           (layer 2, C=64)
template <int C, bool ACCUM>
__global__ __launch_bounds__(TBLOCK) void gatherb_k(const ushort* __restrict__ feat,
                                                    const int* __restrict__ csr,
                                                    const int* __restrict__ offs,
                                                    const int* __restrict__ degi,
                                                    const float* __restrict__ invdeg,
                                                    ushort* __restrict__ outB,
                                                    float* __restrict__ outF, int N) {
    constexpr int G = C / 8;                  // lanes per node, 16B bf16x8 each
    constexpr int NPB = TBLOCK / G;
    int n = blockIdx.x * NPB + threadIdx.x / G;
    if (n >= N) return;
    int lane = threadIdx.x % G;
    int c = lane * 8;
    int s0 = offs[n];
    int d = degi[n];
    float acc[8] = {0.f, 0.f, 0.f, 0.f, 0.f, 0.f, 0.f, 0.f};
    for (int base = 0; base < d; base += G) {
        int rem = d - base;
        int my = (lane < rem) ? csr[s0 + base + lane] : 0;
        if (rem >= G) {
#pragma unroll
            for (int j = 0; j < G; j++) {
                int s = __shfl(my, j, G);
                short8 v = *(const short8*)(feat + (size_t)s * C + c);
#pragma unroll
                for (int q = 0; q < 8; q++) acc[q] += bf2f((ushort)v[q]);
            }
        } else {
            for (int j = 0; j < rem; j++) {
                int s = __shfl(my, j, G);
                short8 v = *(const short8*)(feat + (size_t)s * C + c);
#pragma unroll
                for (int q = 0; q < 8; q++) acc[q] += bf2f((ushort)v[q]);
            }
        }
    }
    float sc = invdeg[n];
    if (ACCUM) {
        float* o = outF + (size_t)n * C + c;
        float4 p0 = *(float4*)o;
        float4 p1 = *(float4*)(o + 4);
        p0.x += sc * acc[0]; p0.y += sc * acc[1]; p0.z += sc * acc[2]; p0.w += sc * acc[3];
        p1.x += sc * acc[4]; p1.y += sc * acc[5]; p1.z += sc * acc[6]; p1.w += sc * acc[7];
        *(float4*)o = p0;
        *(float4*)(o + 4) = p1;
    } else {
        short8 o;
#pragma unroll
        for (int q = 0; q < 8; q++) o[q] = f2bf(sc * acc[q]);
        *(short8*)(outB + (size_t)n * C + c) = o;
    }
}

// ---- MFMA bf16 GEMM: [N_rows x KTOT] @ [KTOT x 128] -----------------------
// mfma_f32_16x16x32_bf16 verified layouts (m89/m91):
//   A frag: lane L holds A[m=L&15][k = (L>>4)*8 + j], j=0..7
//   B frag: lane L holds B[k = (L>>4)*8 + j][n=L&15]  (chunk-major sW gives 16B reads)
//   C/D:    reg r -> row=(L>>4)*4+r, col=L&15
// Each wave: 32 rows (2 M-tiles) x full N=128 (8 N-tiles), K-loop step 32.
// EPI=1: outB = bf16(relu(acc + bias[n]))               (h, 128 cols)
// EPI=2: n<64 -> outB=bf16(acc) (t2b); n>=64 -> outF=acc+bias[n-64] (out, fp32)
template <int KTOT, int EPI>
__global__ __launch_bounds__(TBLOCK) void gemm_k(const ushort* __restrict__ A0,
                                                 const ushort* __restrict__ A1,
                                                 const ushort* __restrict__ wc,
                                                 const float* __restrict__ bias,
                                                 ushort* __restrict__ outB,
                                                 float* __restrict__ outF, int N) {
    __shared__ __align__(16) ushort sW[KTOT * 128];
    for (int i = threadIdx.x * 8; i < KTOT * 128; i += TBLOCK * 8)
        *(short8*)&sW[i] = *(const short8*)&wc[i];
    __syncthreads();

    const int wave = threadIdx.x >> 6;
    const int lane = threadIdx.x & 63;
    const int quad = lane >> 4;
    const int l16 = lane & 15;
    const int m0 = (blockIdx.x * 4 + wave) * 32;
    if (m0 >= N) return;

    f32x4 acc[2][8];
#pragma unroll
    for (int t = 0; t < 2; t++)
#pragma unroll
        for (int nt = 0; nt < 8; nt++) acc[t][nt] = (f32x4){0.f, 0.f, 0.f, 0.f};

    const int k0q = quad * 8;
#pragma unroll
    for (int kb = 0; kb < KTOT; kb += 32) {
        int k = kb + k0q;
        const ushort* abase = (KTOT == 256 && k >= 128) ? (A1 + (k - 128)) : (A0 + k);
        short8 a[2];
#pragma unroll
        for (int t = 0; t < 2; t++) {
            int m = m0 + t * 16 + l16;
            if (m > N - 1) m = N - 1;
            a[t] = *(const short8*)(abase + (size_t)m * 128);
        }
#pragma unroll
        for (int nt = 0; nt < 8; nt++) {
            short8 b = *(const short8*)&sW[((k >> 3) * 128 + nt * 16 + l16) * 8];
            acc[0][nt] = __builtin_amdgcn_mfma_f32_16x16x32_bf16(a[0], b, acc[0][nt], 0, 0, 0);
            acc[1][nt] = __builtin_amdgcn_mfma_f32_16x16x32_bf16(a[1], b, acc[1][nt], 0, 0, 0);
        }
    }

#pragma unroll
    for (int t = 0; t < 2; t++) {
#pragma unroll
        for (int r = 0; r < 4; r++) {
            int m = m0 + t * 16 + quad * 4 + r;
            if (m >= N) continue;
#pragma unroll
            for (int nt = 0; nt < 8; nt++) {
                int n = nt * 16 + l16;
                float v = acc[t][nt][r];
                if (EPI == 1) {
                    v = fmaxf(v + bias[n], 0.f);
                    outB[(size_t)m * 128 + n] = f2bf(v);
                } else {
                    if (n < 64) outB[(size_t)m * 64 + n] = f2bf(v);
                    else outF[(size_t)m * 64 + (n - 64)] = v + bias[n - 64];
                }
            }
        }
    }
}

extern "C" void kernel_launch(void* const* d_in, const int* in_sizes, int n_in,
                              void* d_out, int out_size, void* d_ws, size_t ws_size,
                              hipStream_t stream) {
    const float* x = (const float*)d_in[0];
    const int* edges = (const int*)d_in[1];
    const float* W1l = (const float*)d_in[2];
    const float* b1 = (const float*)d_in[3];
    const float* W1r = (const float*)d_in[4];
    const float* W2l = (const float*)d_in[5];
    const float* b2 = (const float*)d_in[6];
    const float* W2r = (const float*)d_in[7];
    float* out = (float*)d_out;

    const int N = in_sizes[0] / 128;   // 50000
    const int E = in_sizes[1] / 2;     // 800000
    const int Na = (N + 63) & ~63;
    const int NB = (N + CHUNK - 1) / CHUNK;   // 49 (<256 for scan2)

    // ---- workspace layout (bytes, 256B-aligned regions) ----
    char* W = (char*)d_ws;
    size_t off = 0;
    auto alloc = [&](size_t bytes) {
        void* p = W + off;
        off = (off + bytes + 255) & ~(size_t)255;
        return p;
    };
    int* flag = (int*)alloc(4);
    int* degi = (int*)alloc((size_t)Na * 4);
    int* cursor = (int*)alloc((size_t)Na * 4);
    size_t zbytes = off;                       // zero: flag + degi + cursor
    int* partial = (int*)alloc(1024);
    int* offs = (int*)alloc((size_t)Na * 4);
    float* invdeg = (float*)alloc((size_t)Na * 4);
    int* csr = (int*)alloc((size_t)E * 4);
    ushort* xb = (ushort*)alloc((size_t)N * 128 * 2);
    ushort* agg1b = (ushort*)alloc((size_t)N * 128 * 2);
    ushort* hb = (ushort*)alloc((size_t)N * 128 * 2);
    ushort* t2b = (ushort*)alloc((size_t)N * 64 * 2);
    ushort* wc1 = (ushort*)alloc(32768 * 2);
    ushort* wc2 = (ushort*)alloc(16384 * 2);

    hipMemsetAsync(d_ws, 0, zbytes, stream);

    detect_k<<<1, TBLOCK, 0, stream>>>(edges, flag);
    degi_k<<<(E + TBLOCK - 1) / TBLOCK, TBLOCK, 0, stream>>>(edges, E, flag, degi);
    scan1_k<<<NB, TBLOCK, 0, stream>>>(degi, offs, partial, N);
    scan2_k<<<1, TBLOCK, 0, stream>>>(partial, NB);
    scan3_k<<<NB, TBLOCK, 0, stream>>>(offs, partial, degi, invdeg, N);
    fill_k<<<(E + TBLOCK - 1) / TBLOCK, TBLOCK, 0, stream>>>(edges, E, flag, offs, cursor, csr);

    cvtx_k<<<(N * 128 / 8 + TBLOCK - 1) / TBLOCK, TBLOCK, 0, stream>>>(x, xb, N * 128 / 8);
    cvtw_k<<<192, TBLOCK, 0, stream>>>(W1l, W1r, W2l, W2r, wc1, wc2);

    // layer 1: agg1b = bf16(mean_agg(xb))
    gatherb_k<128, false><<<(N + 15) / 16, TBLOCK, 0, stream>>>(
        xb, csr, offs, degi, invdeg, agg1b, nullptr, N);
    // hb = bf16(relu([agg1b | xb] @ [W1l; W1r] + b1))
    gemm_k<256, 1><<<(N + 127) / 128, TBLOCK, 0, stream>>>(
        agg1b, xb, wc1, b1, hb, nullptr, N);

    // layer 2: t2b = bf16(hb @ W2l); out = hb @ W2r + b2
    gemm_k<128, 2><<<(N + 127) / 128, TBLOCK, 0, stream>>>(
        hb, nullptr, wc2, b2, t2b, out, N);
    // out += mean_agg(t2b)
    gatherb_k<64, true><<<(N + 31) / 32, TBLOCK, 0, stream>>>(
        t2b, csr, offs, degi, invdeg, nullptr, out, N);
}

// Round 4
// 229.345 us; speedup vs baseline: 10.0370x; 1.1051x over previous
//
#include <hip/hip_runtime.h>
#include <hip/hip_bf16.h>

// GraphSAGE 2-layer on MI355X.
//   h   = relu(mean_agg(x) @ W1l + b1 + x @ W1r)
//   out = mean_agg(h @ W2l) + b2 + h @ W2r          (aggregate AFTER transform: 64ch)
// R2: CSR-gather replaced atomic scatter (2302 -> 387 us).
// R3: bf16 gathers + MFMA bf16 GEMMs (387 -> 253 us).
// R4: CSR build rebuilt as bucketed 2-pass (bucket = dst>>8, 256 nodes):
//     fill_k's 55 MB of random 4B line-dirtying stores + 1.6M per-edge atomics
//     -> packed 4B records in contiguous runs + per-bucket L2-hot scatter.

#define TBLOCK 256
#define MAXBUCK 1024   // supports N <= 262144

typedef __attribute__((ext_vector_type(8))) short short8;
typedef __attribute__((ext_vector_type(4))) float f32x4;

__device__ __forceinline__ float bf2f(ushort u) {
    union { unsigned int i; float f; } v;
    v.i = (unsigned int)u << 16;
    return v.f;
}
__device__ __forceinline__ ushort f2bf(float f) {  // RTNE
    union { float f; unsigned int u; } v;
    v.f = f;
    unsigned int r = v.u + 0x7fffu + ((v.u >> 16) & 1u);
    return (ushort)(r >> 16);
}

// ---- edge-index dtype detection: int32 vs int64 --------------------------
__global__ void detect_k(const int* __restrict__ edges, int* __restrict__ flag) {
    int tid = threadIdx.x;
    int bad = 0;
    for (int i = tid; i < 2048; i += TBLOCK)
        if (edges[2 * i + 1] != 0) bad = 1;
    unsigned long long b = __ballot(bad);
    __shared__ int sbad[4];
    int w = tid >> 6;
    if ((tid & 63) == 0) sbad[w] = (b != 0) ? 1 : 0;
    __syncthreads();
    if (tid == 0) flag[0] = (sbad[0] | sbad[1] | sbad[2] | sbad[3]) ? 0 : 1;
}

__device__ __forceinline__ int load_src(const int* e, long long i, int E, int is64) {
    return is64 ? e[2 * i] : e[i];
}
__device__ __forceinline__ int load_dst(const int* e, long long i, int E, int is64) {
    return is64 ? e[2 * (long long)E + 2 * i] : e[(long long)E + i];
}

// ---- pass A0: per-bucket histogram (bucket = dst >> 8) --------------------
__global__ __launch_bounds__(TBLOCK) void histA_k(const int* __restrict__ edges, int E,
                                                  const int* __restrict__ flag,
                                                  int* __restrict__ hist, int NBUCK) {
    __shared__ int lh[MAXBUCK];
    int t = threadIdx.x;
    for (int i = t; i < NBUCK; i += TBLOCK) lh[i] = 0;
    __syncthreads();
    int is64 = flag[0];
    int per = (E + gridDim.x - 1) / gridDim.x;
    int b0 = blockIdx.x * per, b1 = min(E, b0 + per);
    for (int i = b0 + t; i < b1; i += TBLOCK) {
        int d = load_dst(edges, i, E, is64);
        atomicAdd(&lh[d >> 8], 1);
    }
    __syncthreads();
    for (int i = t; i < NBUCK; i += TBLOCK)
        if (lh[i]) atomicAdd(&hist[i], lh[i]);
}

// ---- pass A0.5: exclusive scan of bucket counts (1 block, NBUCK<=1024) ----
__global__ __launch_bounds__(TBLOCK) void scanB_k(const int* __restrict__ hist,
                                                  int* __restrict__ base,
                                                  int* __restrict__ cursor, int NBUCK) {
    __shared__ int s[TBLOCK];
    int t = threadIdx.x;
    int v[4];
    int sum = 0;
#pragma unroll
    for (int i = 0; i < 4; i++) {
        int idx = t * 4 + i;
        int d = (idx < NBUCK) ? hist[idx] : 0;
        v[i] = sum;
        sum += d;
    }
    s[t] = sum;
    __syncthreads();
    for (int off = 1; off < TBLOCK; off <<= 1) {
        int x = (t >= off) ? s[t - off] : 0;
        __syncthreads();
        s[t] += x;
        __syncthreads();
    }
    int excl = (t == 0) ? 0 : s[t - 1];
#pragma unroll
    for (int i = 0; i < 4; i++) {
        int idx = t * 4 + i;
        if (idx < NBUCK) {
            int b = excl + v[i];
            base[idx] = b;
            cursor[idx] = b;
        }
    }
    if (t == TBLOCK - 1) base[NBUCK] = s[TBLOCK - 1];
}

// ---- pass A1: bucket-grouped packed records -------------------------------
// packed = src | (dst&255)<<24 ; per-block contiguous runs per bucket.
__global__ __launch_bounds__(TBLOCK) void scatterA_k(const int* __restrict__ edges, int E,
                                                     const int* __restrict__ flag,
                                                     int* __restrict__ cursor,
                                                     unsigned int* __restrict__ packed,
                                                     int NBUCK) {
    __shared__ int lh[MAXBUCK];
    __shared__ int lb[MAXBUCK];
    int t = threadIdx.x;
    for (int i = t; i < NBUCK; i += TBLOCK) lh[i] = 0;
    __syncthreads();
    int is64 = flag[0];
    int per = (E + gridDim.x - 1) / gridDim.x;
    int b0 = blockIdx.x * per, b1 = min(E, b0 + per);
    for (int i = b0 + t; i < b1; i += TBLOCK) {
        int d = load_dst(edges, i, E, is64);
        atomicAdd(&lh[d >> 8], 1);
    }
    __syncthreads();
    for (int i = t; i < NBUCK; i += TBLOCK) {
        int c = lh[i];
        lb[i] = c ? atomicAdd(&cursor[i], c) : 0;
        lh[i] = 0;
    }
    __syncthreads();
    for (int i = b0 + t; i < b1; i += TBLOCK) {
        int s = load_src(edges, i, E, is64);
        int d = load_dst(edges, i, E, is64);
        int b = d >> 8;
        int pos = lb[b] + atomicAdd(&lh[b], 1);
        packed[pos] = (unsigned int)s | ((unsigned int)(d & 255) << 24);
    }
}

// ---- pass B: per-bucket CSR finalize (one workgroup per bucket) -----------
__global__ __launch_bounds__(TBLOCK) void buildB_k(const unsigned int* __restrict__ packed,
                                                   const int* __restrict__ base,
                                                   int* __restrict__ offs,
                                                   int* __restrict__ degi,
                                                   float* __restrict__ invdeg,
                                                   int* __restrict__ csr, int N) {
    __shared__ int cnt[TBLOCK], scn[TBLOCK], cur[TBLOCK];
    int t = threadIdx.x;
    int bucket = blockIdx.x;
    int e0 = base[bucket], e1 = base[bucket + 1];
    cnt[t] = 0;
    cur[t] = 0;
    __syncthreads();
    for (int i = e0 + t; i < e1; i += TBLOCK)
        atomicAdd(&cnt[packed[i] >> 24], 1);
    __syncthreads();
    scn[t] = cnt[t];
    __syncthreads();
    for (int off = 1; off < TBLOCK; off <<= 1) {
        int x = (t >= off) ? scn[t - off] : 0;
        __syncthreads();
        scn[t] += x;
        __syncthreads();
    }
    int excl = (t == 0) ? 0 : scn[t - 1];
    int node = bucket * 256 + t;
    if (node < N) {
        offs[node] = e0 + excl;
        degi[node] = cnt[t];
        invdeg[node] = 1.0f / fmaxf((float)cnt[t], 1.0f);
    }
    __syncthreads();
    cnt[t] = excl;               // reuse as per-node exclusive base
    __syncthreads();
    for (int i = e0 + t; i < e1; i += TBLOCK) {
        unsigned int p = packed[i];
        int nl = p >> 24;
        int pos = e0 + cnt[nl] + atomicAdd(&cur[nl], 1);
        csr[pos] = (int)(p & 0xFFFFFFu);
    }
}

// ---- x (fp32) -> xb (bf16), 8 elements/thread -----------------------------
__global__ __launch_bounds__(TBLOCK) void cvtx_k(const float* __restrict__ x,
                                                 ushort* __restrict__ xb, int n8) {
    int i = blockIdx.x * TBLOCK + threadIdx.x;
    if (i >= n8) return;
    const float4* p = (const float4*)x + (size_t)i * 2;
    float4 a = p[0], b = p[1];
    short8 o;
    o[0] = f2bf(a.x); o[1] = f2bf(a.y); o[2] = f2bf(a.z); o[3] = f2bf(a.w);
    o[4] = f2bf(b.x); o[5] = f2bf(b.y); o[6] = f2bf(b.z); o[7] = f2bf(b.w);
    *(short8*)(xb + (size_t)i * 8) = o;
}

// ---- weight prep: transpose+concat to bf16 chunk-major --------------------
// wc[((k>>3)*128 + n)*8 + (k&7)] = W[k][n]; B-frag load = contiguous 16B.
// wc1: K=256, Wcat1[k][n] = k<128 ? W1l[k][n] : W1r[k-128][n]      (N=128)
// wc2: K=128, Wcat2[k][n] = n<64  ? W2l[k][n] : W2r[k][n-64]       (N=128)
__global__ __launch_bounds__(TBLOCK) void cvtw_k(const float* __restrict__ W1l,
                                                 const float* __restrict__ W1r,
                                                 const float* __restrict__ W2l,
                                                 const float* __restrict__ W2r,
                                                 ushort* __restrict__ wc1,
                                                 ushort* __restrict__ wc2) {
    int i = blockIdx.x * TBLOCK + threadIdx.x;
    if (i < 32768) {
        int j = i & 7;
        int rest = i >> 3;
        int n = rest & 127;
        int k = ((rest >> 7) << 3) | j;
        float w = (k < 128) ? W1l[k * 128 + n] : W1r[(k - 128) * 128 + n];
        wc1[i] = f2bf(w);
    } else if (i < 49152) {
        int i2 = i - 32768;
        int j = i2 & 7;
        int rest = i2 >> 3;
        int n = rest & 127;
        int k = ((rest >> 7) << 3) | j;
        float w = (n < 64) ? W2l[k * 64 + n] : W2r[k * 64 + (n - 64)];
        wc2[i2] = f2bf(w);
    }
}

// ---- gather-aggregate over bf16 features ---------------------------------
// ACCUM=0: outB[n][:] = bf16(invdeg[n] * sum feat[src])      (layer 1, C=128)
// ACCUM=1: outF[n][:] += invdeg[n] * sum feat[src]           (layer 2, C=64)
template <int C, bool ACCUM>
__global__ __launch_bounds__(TBLOCK) void gatherb_k(const ushort* __restrict__ feat,
                                                    const int* __restrict__ csr,
                                                    const int* __restrict__ offs,
                                                    const int* __restrict__ degi,
                                                    const float* __restrict__ invdeg,
                                                    ushort* __restrict__ outB,
                                                    float* __restrict__ outF, int N) {
    constexpr int G = C / 8;                  // lanes per node, 16B bf16x8 each
    constexpr int NPB = TBLOCK / G;
    int n = blockIdx.x * NPB + threadIdx.x / G;
    if (n >= N) return;
    int lane = threadIdx.x % G;
    int c = lane * 8;
    int s0 = offs[n];
    int d = degi[n];
    float acc[8] = {0.f, 0.f, 0.f, 0.f, 0.f, 0.f, 0.f, 0.f};
    for (int base = 0; base < d; base += G) {
        int rem = d - base;
        int my = (lane < rem) ? csr[s0 + base + lane] : 0;
        if (rem >= G) {
#pragma unroll
            for (int j = 0; j < G; j++) {
                int s = __shfl(my, j, G);
                short8 v = *(const short8*)(feat + (size_t)s * C + c);
#pragma unroll
                for (int q = 0; q < 8; q++) acc[q] += bf2f((ushort)v[q]);
            }
        } else {
            for (int j = 0; j < rem; j++) {
                int s = __shfl(my, j, G);
                short8 v = *(const short8*)(feat + (size_t)s * C + c);
#pragma unroll
                for (int q = 0; q < 8; q++) acc[q] += bf2f((ushort)v[q]);
            }
        }
    }
    float sc = invdeg[n];
    if (ACCUM) {
        float* o = outF + (size_t)n * C + c;
        float4 p0 = *(float4*)o;
        float4 p1 = *(float4*)(o + 4);
        p0.x += sc * acc[0]; p0.y += sc * acc[1]; p0.z += sc * acc[2]; p0.w += sc * acc[3];
        p1.x += sc * acc[4]; p1.y += sc * acc[5]; p1.z += sc * acc[6]; p1.w += sc * acc[7];
        *(float4*)o = p0;
        *(float4*)(o + 4) = p1;
    } else {
        short8 o;
#pragma unroll
        for (int q = 0; q < 8; q++) o[q] = f2bf(sc * acc[q]);
        *(short8*)(outB + (size_t)n * C + c) = o;
    }
}

// ---- MFMA bf16 GEMM: [N_rows x KTOT] @ [KTOT x 128] -----------------------
// mfma_f32_16x16x32_bf16 verified layouts (m89/m91):
//   A frag: lane L holds A[m=L&15][k = (L>>4)*8 + j], j=0..7
//   B frag: lane L holds B[k = (L>>4)*8 + j][n=L&15]  (chunk-major sW: 16B reads)
//   C/D:    reg r -> row=(L>>4)*4+r, col=L&15
// EPI=1: outB = bf16(relu(acc + bias[n]))               (h, 128 cols)
// EPI=2: n<64 -> outB=bf16(acc) (t2b); n>=64 -> outF=acc+bias[n-64] (out, fp32)
template <int KTOT, int EPI>
__global__ __launch_bounds__(TBLOCK) void gemm_k(const ushort* __restrict__ A0,
                                                 const ushort* __restrict__ A1,
                                                 const ushort* __restrict__ wc,
                                                 const float* __restrict__ bias,
                                                 ushort* __restrict__ outB,
                                                 float* __restrict__ outF, int N) {
    __shared__ __align__(16) ushort sW[KTOT * 128];
    for (int i = threadIdx.x * 8; i < KTOT * 128; i += TBLOCK * 8)
        *(short8*)&sW[i] = *(const short8*)&wc[i];
    __syncthreads();

    const int wave = threadIdx.x >> 6;
    const int lane = threadIdx.x & 63;
    const int quad = lane >> 4;
    const int l16 = lane & 15;
    const int m0 = (blockIdx.x * 4 + wave) * 32;
    if (m0 >= N) return;

    f32x4 acc[2][8];
#pragma unroll
    for (int t = 0; t < 2; t++)
#pragma unroll
        for (int nt = 0; nt < 8; nt++) acc[t][nt] = (f32x4){0.f, 0.f, 0.f, 0.f};

    const int k0q = quad * 8;
#pragma unroll
    for (int kb = 0; kb < KTOT; kb += 32) {
        int k = kb + k0q;
        const ushort* abase = (KTOT == 256 && k >= 128) ? (A1 + (k - 128)) : (A0 + k);
        short8 a[2];
#pragma unroll
        for (int t = 0; t < 2; t++) {
            int m = m0 + t * 16 + l16;
            if (m > N - 1) m = N - 1;
            a[t] = *(const short8*)(abase + (size_t)m * 128);
        }
#pragma unroll
        for (int nt = 0; nt < 8; nt++) {
            short8 b = *(const short8*)&sW[((k >> 3) * 128 + nt * 16 + l16) * 8];
            acc[0][nt] = __builtin_amdgcn_mfma_f32_16x16x32_bf16(a[0], b, acc[0][nt], 0, 0, 0);
            acc[1][nt] = __builtin_amdgcn_mfma_f32_16x16x32_bf16(a[1], b, acc[1][nt], 0, 0, 0);
        }
    }

#pragma unroll
    for (int t = 0; t < 2; t++) {
#pragma unroll
        for (int r = 0; r < 4; r++) {
            int m = m0 + t * 16 + quad * 4 + r;
            if (m >= N) continue;
#pragma unroll
            for (int nt = 0; nt < 8; nt++) {
                int n = nt * 16 + l16;
                float v = acc[t][nt][r];
                if (EPI == 1) {
                    v = fmaxf(v + bias[n], 0.f);
                    outB[(size_t)m * 128 + n] = f2bf(v);
                } else {
                    if (n < 64) outB[(size_t)m * 64 + n] = f2bf(v);
                    else outF[(size_t)m * 64 + (n - 64)] = v + bias[n - 64];
                }
            }
        }
    }
}

extern "C" void kernel_launch(void* const* d_in, const int* in_sizes, int n_in,
                              void* d_out, int out_size, void* d_ws, size_t ws_size,
                              hipStream_t stream) {
    const float* x = (const float*)d_in[0];
    const int* edges = (const int*)d_in[1];
    const float* W1l = (const float*)d_in[2];
    const float* b1 = (const float*)d_in[3];
    const float* W1r = (const float*)d_in[4];
    const float* W2l = (const float*)d_in[5];
    const float* b2 = (const float*)d_in[6];
    const float* W2r = (const float*)d_in[7];
    float* out = (float*)d_out;

    const int N = in_sizes[0] / 128;   // 50000
    const int E = in_sizes[1] / 2;     // 800000
    const int Na = (N + 63) & ~63;
    const int NBUCK = (N + 255) >> 8;  // 196

    // ---- workspace layout (bytes, 256B-aligned regions) ----
    char* W = (char*)d_ws;
    size_t off = 0;
    auto alloc = [&](size_t bytes) {
        void* p = W + off;
        off = (off + bytes + 255) & ~(size_t)255;
        return p;
    };
    int* flag = (int*)alloc(4);
    int* hist = (int*)alloc((size_t)MAXBUCK * 4);
    size_t zbytes = off;                       // zero: flag + hist
    int* base = (int*)alloc((size_t)(MAXBUCK + 1) * 4);
    int* cursor = (int*)alloc((size_t)MAXBUCK * 4);
    int* offs = (int*)alloc((size_t)Na * 4);
    int* degi = (int*)alloc((size_t)Na * 4);
    float* invdeg = (float*)alloc((size_t)Na * 4);
    unsigned int* packed = (unsigned int*)alloc((size_t)E * 4);
    int* csr = (int*)alloc((size_t)E * 4);
    ushort* xb = (ushort*)alloc((size_t)N * 128 * 2);
    ushort* agg1b = (ushort*)alloc((size_t)N * 128 * 2);
    ushort* hb = (ushort*)alloc((size_t)N * 128 * 2);
    ushort* t2b = (ushort*)alloc((size_t)N * 64 * 2);
    ushort* wc1 = (ushort*)alloc(32768 * 2);
    ushort* wc2 = (ushort*)alloc(16384 * 2);

    hipMemsetAsync(d_ws, 0, zbytes, stream);

    detect_k<<<1, TBLOCK, 0, stream>>>(edges, flag);
    histA_k<<<64, TBLOCK, 0, stream>>>(edges, E, flag, hist, NBUCK);
    scanB_k<<<1, TBLOCK, 0, stream>>>(hist, base, cursor, NBUCK);
    scatterA_k<<<64, TBLOCK, 0, stream>>>(edges, E, flag, cursor, packed, NBUCK);
    buildB_k<<<NBUCK, TBLOCK, 0, stream>>>(packed, base, offs, degi, invdeg, csr, N);

    cvtx_k<<<(N * 128 / 8 + TBLOCK - 1) / TBLOCK, TBLOCK, 0, stream>>>(x, xb, N * 128 / 8);
    cvtw_k<<<192, TBLOCK, 0, stream>>>(W1l, W1r, W2l, W2r, wc1, wc2);

    // layer 1: agg1b = bf16(mean_agg(xb))
    gatherb_k<128, false><<<(N + 15) / 16, TBLOCK, 0, stream>>>(
        xb, csr, offs, degi, invdeg, agg1b, nullptr, N);
    // hb = bf16(relu([agg1b | xb] @ [W1l; W1r] + b1))
    gemm_k<256, 1><<<(N + 127) / 128, TBLOCK, 0, stream>>>(
        agg1b, xb, wc1, b1, hb, nullptr, N);

    // layer 2: t2b = bf16(hb @ W2l); out = hb @ W2r + b2
    gemm_k<128, 2><<<(N + 127) / 128, TBLOCK, 0, stream>>>(
        hb, nullptr, wc2, b2, t2b, out, N);
    // out += mean_agg(t2b)
    gatherb_k<64, true><<<(N + 31) / 32, TBLOCK, 0, stream>>>(
        t2b, csr, offs, degi, invdeg, nullptr, out, N);
}

// Round 5
// 215.926 us; speedup vs baseline: 10.6607x; 1.0621x over previous
//
#include <hip/hip_runtime.h>
#include <hip/hip_bf16.h>

// GraphSAGE 2-layer on MI355X.
//   h   = relu(mean_agg(x) @ W1l + b1 + x @ W1r)
//   out = mean_agg(h @ W2l) + b2 + h @ W2r          (aggregate AFTER transform: 64ch)
// R2: CSR-gather replaced atomic scatter (2302 -> 387 us).
// R3: bf16 gathers + MFMA bf16 GEMMs (387 -> 253 us).
// R4: bucketed 2-pass CSR build (253 -> 229 us).
// R5: scatterA/histA grid 64 -> 512 (they were 2.5% occupancy, 75 us combined);
//     detect folded into edge kernels; cvtx+cvtw merged.

#define TBLOCK 256
#define MAXBUCK 1024   // supports N <= 262144
#define BUILD_GRID 512

typedef __attribute__((ext_vector_type(8))) short short8;
typedef __attribute__((ext_vector_type(4))) float f32x4;

__device__ __forceinline__ float bf2f(ushort u) {
    union { unsigned int i; float f; } v;
    v.i = (unsigned int)u << 16;
    return v.f;
}
__device__ __forceinline__ ushort f2bf(float f) {  // RTNE
    union { float f; unsigned int u; } v;
    v.f = f;
    unsigned int r = v.u + 0x7fffu + ((v.u >> 16) & 1u);
    return (ushort)(r >> 16);
}

// ---- per-block edge-index dtype detection (int32 vs int64) ----------------
// int64 little-endian with values < 2^31 => every odd int32 word is zero.
__device__ __forceinline__ int block_detect_is64(const int* __restrict__ edges) {
    __shared__ int sbad[4];
    __shared__ int sflag;
    int tid = threadIdx.x;
    int bad = 0;
    for (int i = tid; i < 2048; i += TBLOCK)
        if (edges[2 * i + 1] != 0) bad = 1;
    unsigned long long b = __ballot(bad);
    if ((tid & 63) == 0) sbad[tid >> 6] = (b != 0) ? 1 : 0;
    __syncthreads();
    if (tid == 0) sflag = (sbad[0] | sbad[1] | sbad[2] | sbad[3]) ? 0 : 1;
    __syncthreads();
    return sflag;
}

__device__ __forceinline__ int load_src(const int* e, long long i, int E, int is64) {
    return is64 ? e[2 * i] : e[i];
}
__device__ __forceinline__ int load_dst(const int* e, long long i, int E, int is64) {
    return is64 ? e[2 * (long long)E + 2 * i] : e[(long long)E + i];
}

// ---- pass A0: per-bucket histogram (bucket = dst >> 8) --------------------
__global__ __launch_bounds__(TBLOCK) void histA_k(const int* __restrict__ edges, int E,
                                                  int* __restrict__ hist, int NBUCK) {
    int is64 = block_detect_is64(edges);
    __shared__ int lh[MAXBUCK];
    int t = threadIdx.x;
    for (int i = t; i < NBUCK; i += TBLOCK) lh[i] = 0;
    __syncthreads();
    int per = (E + gridDim.x - 1) / gridDim.x;
    int b0 = blockIdx.x * per, b1 = min(E, b0 + per);
    for (int i = b0 + t; i < b1; i += TBLOCK) {
        int d = load_dst(edges, i, E, is64);
        atomicAdd(&lh[d >> 8], 1);
    }
    __syncthreads();
    for (int i = t; i < NBUCK; i += TBLOCK)
        if (lh[i]) atomicAdd(&hist[i], lh[i]);
}

// ---- pass A0.5: exclusive scan of bucket counts (1 block, NBUCK<=1024) ----
__global__ __launch_bounds__(TBLOCK) void scanB_k(const int* __restrict__ hist,
                                                  int* __restrict__ base,
                                                  int* __restrict__ cursor, int NBUCK) {
    __shared__ int s[TBLOCK];
    int t = threadIdx.x;
    int v[4];
    int sum = 0;
#pragma unroll
    for (int i = 0; i < 4; i++) {
        int idx = t * 4 + i;
        int d = (idx < NBUCK) ? hist[idx] : 0;
        v[i] = sum;
        sum += d;
    }
    s[t] = sum;
    __syncthreads();
    for (int off = 1; off < TBLOCK; off <<= 1) {
        int x = (t >= off) ? s[t - off] : 0;
        __syncthreads();
        s[t] += x;
        __syncthreads();
    }
    int excl = (t == 0) ? 0 : s[t - 1];
#pragma unroll
    for (int i = 0; i < 4; i++) {
        int idx = t * 4 + i;
        if (idx < NBUCK) {
            int b = excl + v[i];
            base[idx] = b;
            cursor[idx] = b;
        }
    }
    if (t == TBLOCK - 1) base[NBUCK] = s[TBLOCK - 1];
}

// ---- pass A1: bucket-grouped packed records -------------------------------
// packed = src | (dst&255)<<24 ; per-block contiguous runs per bucket.
__global__ __launch_bounds__(TBLOCK) void scatterA_k(const int* __restrict__ edges, int E,
                                                     int* __restrict__ cursor,
                                                     unsigned int* __restrict__ packed,
                                                     int NBUCK) {
    int is64 = block_detect_is64(edges);
    __shared__ int lh[MAXBUCK];
    __shared__ int lb[MAXBUCK];
    int t = threadIdx.x;
    for (int i = t; i < NBUCK; i += TBLOCK) lh[i] = 0;
    __syncthreads();
    int per = (E + gridDim.x - 1) / gridDim.x;
    int b0 = blockIdx.x * per, b1 = min(E, b0 + per);
    for (int i = b0 + t; i < b1; i += TBLOCK) {
        int d = load_dst(edges, i, E, is64);
        atomicAdd(&lh[d >> 8], 1);
    }
    __syncthreads();
    for (int i = t; i < NBUCK; i += TBLOCK) {
        int c = lh[i];
        lb[i] = c ? atomicAdd(&cursor[i], c) : 0;
        lh[i] = 0;
    }
    __syncthreads();
    for (int i = b0 + t; i < b1; i += TBLOCK) {
        int s = load_src(edges, i, E, is64);
        int d = load_dst(edges, i, E, is64);
        int b = d >> 8;
        int pos = lb[b] + atomicAdd(&lh[b], 1);
        packed[pos] = (unsigned int)s | ((unsigned int)(d & 255) << 24);
    }
}

// ---- pass B: per-bucket CSR finalize (one workgroup per bucket) -----------
__global__ __launch_bounds__(TBLOCK) void buildB_k(const unsigned int* __restrict__ packed,
                                                   const int* __restrict__ base,
                                                   int* __restrict__ offs,
                                                   int* __restrict__ degi,
                                                   float* __restrict__ invdeg,
                                                   int* __restrict__ csr, int N) {
    __shared__ int cnt[TBLOCK], scn[TBLOCK], cur[TBLOCK];
    int t = threadIdx.x;
    int bucket = blockIdx.x;
    int e0 = base[bucket], e1 = base[bucket + 1];
    cnt[t] = 0;
    cur[t] = 0;
    __syncthreads();
    for (int i = e0 + t; i < e1; i += TBLOCK)
        atomicAdd(&cnt[packed[i] >> 24], 1);
    __syncthreads();
    scn[t] = cnt[t];
    __syncthreads();
    for (int off = 1; off < TBLOCK; off <<= 1) {
        int x = (t >= off) ? scn[t - off] : 0;
        __syncthreads();
        scn[t] += x;
        __syncthreads();
    }
    int excl = (t == 0) ? 0 : scn[t - 1];
    int node = bucket * 256 + t;
    if (node < N) {
        offs[node] = e0 + excl;
        degi[node] = cnt[t];
        invdeg[node] = 1.0f / fmaxf((float)cnt[t], 1.0f);
    }
    __syncthreads();
    cnt[t] = excl;               // reuse as per-node exclusive base
    __syncthreads();
    for (int i = e0 + t; i < e1; i += TBLOCK) {
        unsigned int p = packed[i];
        int nl = p >> 24;
        int pos = e0 + cnt[nl] + atomicAdd(&cur[nl], 1);
        csr[pos] = (int)(p & 0xFFFFFFu);
    }
}

// ---- prep: x -> bf16 (first nxb blocks) + weight transpose/concat ---------
// wc[((k>>3)*128 + n)*8 + (k&7)] = W[k][n]; B-frag load = contiguous 16B.
// wc1: K=256, Wcat1[k][n] = k<128 ? W1l[k][n] : W1r[k-128][n]      (N=128)
// wc2: K=128, Wcat2[k][n] = n<64  ? W2l[k][n] : W2r[k][n-64]       (N=128)
__global__ __launch_bounds__(TBLOCK) void prep_k(const float* __restrict__ x,
                                                 const float* __restrict__ W1l,
                                                 const float* __restrict__ W1r,
                                                 const float* __restrict__ W2l,
                                                 const float* __restrict__ W2r,
                                                 ushort* __restrict__ xb,
                                                 ushort* __restrict__ wc1,
                                                 ushort* __restrict__ wc2,
                                                 int n8, int nxb) {
    if ((int)blockIdx.x < nxb) {
        int i = blockIdx.x * TBLOCK + threadIdx.x;
        if (i >= n8) return;
        const float4* p = (const float4*)x + (size_t)i * 2;
        float4 a = p[0], b = p[1];
        short8 o;
        o[0] = f2bf(a.x); o[1] = f2bf(a.y); o[2] = f2bf(a.z); o[3] = f2bf(a.w);
        o[4] = f2bf(b.x); o[5] = f2bf(b.y); o[6] = f2bf(b.z); o[7] = f2bf(b.w);
        *(short8*)(xb + (size_t)i * 8) = o;
    } else {
        int i = (blockIdx.x - nxb) * TBLOCK + threadIdx.x;
        if (i < 32768) {
            int j = i & 7;
            int rest = i >> 3;
            int n = rest & 127;
            int k = ((rest >> 7) << 3) | j;
            float w = (k < 128) ? W1l[k * 128 + n] : W1r[(k - 128) * 128 + n];
            wc1[i] = f2bf(w);
        } else if (i < 49152) {
            int i2 = i - 32768;
            int j = i2 & 7;
            int rest = i2 >> 3;
            int n = rest & 127;
            int k = ((rest >> 7) << 3) | j;
            float w = (n < 64) ? W2l[k * 64 + n] : W2r[k * 64 + (n - 64)];
            wc2[i2] = f2bf(w);
        }
    }
}

// ---- gather-aggregate over bf16 features ---------------------------------
// ACCUM=0: outB[n][:] = bf16(invdeg[n] * sum feat[src])      (layer 1, C=128)
// ACCUM=1: outF[n][:] += invdeg[n] * sum feat[src]           (layer 2, C=64)
template <int C, bool ACCUM>
__global__ __launch_bounds__(TBLOCK) void gatherb_k(const ushort* __restrict__ feat,
                                                    const int* __restrict__ csr,
                                                    const int* __restrict__ offs,
                                                    const int* __restrict__ degi,
                                                    const float* __restrict__ invdeg,
                                                    ushort* __restrict__ outB,
                                                    float* __restrict__ outF, int N) {
    constexpr int G = C / 8;                  // lanes per node, 16B bf16x8 each
    constexpr int NPB = TBLOCK / G;
    int n = blockIdx.x * NPB + threadIdx.x / G;
    if (n >= N) return;
    int lane = threadIdx.x % G;
    int c = lane * 8;
    int s0 = offs[n];
    int d = degi[n];
    float acc[8] = {0.f, 0.f, 0.f, 0.f, 0.f, 0.f, 0.f, 0.f};
    for (int base = 0; base < d; base += G) {
        int rem = d - base;
        int my = (lane < rem) ? csr[s0 + base + lane] : 0;
        if (rem >= G) {
#pragma unroll
            for (int j = 0; j < G; j++) {
                int s = __shfl(my, j, G);
                short8 v = *(const short8*)(feat + (size_t)s * C + c);
#pragma unroll
                for (int q = 0; q < 8; q++) acc[q] += bf2f((ushort)v[q]);
            }
        } else {
            for (int j = 0; j < rem; j++) {
                int s = __shfl(my, j, G);
                short8 v = *(const short8*)(feat + (size_t)s * C + c);
#pragma unroll
                for (int q = 0; q < 8; q++) acc[q] += bf2f((ushort)v[q]);
            }
        }
    }
    float sc = invdeg[n];
    if (ACCUM) {
        float* o = outF + (size_t)n * C + c;
        float4 p0 = *(float4*)o;
        float4 p1 = *(float4*)(o + 4);
        p0.x += sc * acc[0]; p0.y += sc * acc[1]; p0.z += sc * acc[2]; p0.w += sc * acc[3];
        p1.x += sc * acc[4]; p1.y += sc * acc[5]; p1.z += sc * acc[6]; p1.w += sc * acc[7];
        *(float4*)o = p0;
        *(float4*)(o + 4) = p1;
    } else {
        short8 o;
#pragma unroll
        for (int q = 0; q < 8; q++) o[q] = f2bf(sc * acc[q]);
        *(short8*)(outB + (size_t)n * C + c) = o;
    }
}

// ---- MFMA bf16 GEMM: [N_rows x KTOT] @ [KTOT x 128] -----------------------
// mfma_f32_16x16x32_bf16 verified layouts (m89/m91):
//   A frag: lane L holds A[m=L&15][k = (L>>4)*8 + j], j=0..7
//   B frag: lane L holds B[k = (L>>4)*8 + j][n=L&15]  (chunk-major sW: 16B reads)
//   C/D:    reg r -> row=(L>>4)*4+r, col=L&15
// EPI=1: outB = bf16(relu(acc + bias[n]))               (h, 128 cols)
// EPI=2: n<64 -> outB=bf16(acc) (t2b); n>=64 -> outF=acc+bias[n-64] (out, fp32)
template <int KTOT, int EPI>
__global__ __launch_bounds__(TBLOCK) void gemm_k(const ushort* __restrict__ A0,
                                                 const ushort* __restrict__ A1,
                                                 const ushort* __restrict__ wc,
                                                 const float* __restrict__ bias,
                                                 ushort* __restrict__ outB,
                                                 float* __restrict__ outF, int N) {
    __shared__ __align__(16) ushort sW[KTOT * 128];
    for (int i = threadIdx.x * 8; i < KTOT * 128; i += TBLOCK * 8)
        *(short8*)&sW[i] = *(const short8*)&wc[i];
    __syncthreads();

    const int wave = threadIdx.x >> 6;
    const int lane = threadIdx.x & 63;
    const int quad = lane >> 4;
    const int l16 = lane & 15;
    const int m0 = (blockIdx.x * 4 + wave) * 32;
    if (m0 >= N) return;

    f32x4 acc[2][8];
#pragma unroll
    for (int t = 0; t < 2; t++)
#pragma unroll
        for (int nt = 0; nt < 8; nt++) acc[t][nt] = (f32x4){0.f, 0.f, 0.f, 0.f};

    const int k0q = quad * 8;
#pragma unroll
    for (int kb = 0; kb < KTOT; kb += 32) {
        int k = kb + k0q;
        const ushort* abase = (KTOT == 256 && k >= 128) ? (A1 + (k - 128)) : (A0 + k);
        short8 a[2];
#pragma unroll
        for (int t = 0; t < 2; t++) {
            int m = m0 + t * 16 + l16;
            if (m > N - 1) m = N - 1;
            a[t] = *(const short8*)(abase + (size_t)m * 128);
        }
#pragma unroll
        for (int nt = 0; nt < 8; nt++) {
            short8 b = *(const short8*)&sW[((k >> 3) * 128 + nt * 16 + l16) * 8];
            acc[0][nt] = __builtin_amdgcn_mfma_f32_16x16x32_bf16(a[0], b, acc[0][nt], 0, 0, 0);
            acc[1][nt] = __builtin_amdgcn_mfma_f32_16x16x32_bf16(a[1], b, acc[1][nt], 0, 0, 0);
        }
    }

#pragma unroll
    for (int t = 0; t < 2; t++) {
#pragma unroll
        for (int r = 0; r < 4; r++) {
            int m = m0 + t * 16 + quad * 4 + r;
            if (m >= N) continue;
#pragma unroll
            for (int nt = 0; nt < 8; nt++) {
                int n = nt * 16 + l16;
                float v = acc[t][nt][r];
                if (EPI == 1) {
                    v = fmaxf(v + bias[n], 0.f);
                    outB[(size_t)m * 128 + n] = f2bf(v);
                } else {
                    if (n < 64) outB[(size_t)m * 64 + n] = f2bf(v);
                    else outF[(size_t)m * 64 + (n - 64)] = v + bias[n - 64];
                }
            }
        }
    }
}

extern "C" void kernel_launch(void* const* d_in, const int* in_sizes, int n_in,
                              void* d_out, int out_size, void* d_ws, size_t ws_size,
                              hipStream_t stream) {
    const float* x = (const float*)d_in[0];
    const int* edges = (const int*)d_in[1];
    const float* W1l = (const float*)d_in[2];
    const float* b1 = (const float*)d_in[3];
    const float* W1r = (const float*)d_in[4];
    const float* W2l = (const float*)d_in[5];
    const float* b2 = (const float*)d_in[6];
    const float* W2r = (const float*)d_in[7];
    float* out = (float*)d_out;

    const int N = in_sizes[0] / 128;   // 50000
    const int E = in_sizes[1] / 2;     // 800000
    const int Na = (N + 63) & ~63;
    const int NBUCK = (N + 255) >> 8;  // 196

    // ---- workspace layout (bytes, 256B-aligned regions) ----
    char* W = (char*)d_ws;
    size_t off = 0;
    auto alloc = [&](size_t bytes) {
        void* p = W + off;
        off = (off + bytes + 255) & ~(size_t)255;
        return p;
    };
    int* hist = (int*)alloc((size_t)MAXBUCK * 4);
    size_t zbytes = off;                       // zero: hist only
    int* base = (int*)alloc((size_t)(MAXBUCK + 1) * 4);
    int* cursor = (int*)alloc((size_t)MAXBUCK * 4);
    int* offs = (int*)alloc((size_t)Na * 4);
    int* degi = (int*)alloc((size_t)Na * 4);
    float* invdeg = (float*)alloc((size_t)Na * 4);
    unsigned int* packed = (unsigned int*)alloc((size_t)E * 4);
    int* csr = (int*)alloc((size_t)E * 4);
    ushort* xb = (ushort*)alloc((size_t)N * 128 * 2);
    ushort* agg1b = (ushort*)alloc((size_t)N * 128 * 2);
    ushort* hb = (ushort*)alloc((size_t)N * 128 * 2);
    ushort* t2b = (ushort*)alloc((size_t)N * 64 * 2);
    ushort* wc1 = (ushort*)alloc(32768 * 2);
    ushort* wc2 = (ushort*)alloc(16384 * 2);

    hipMemsetAsync(d_ws, 0, zbytes, stream);

    histA_k<<<BUILD_GRID, TBLOCK, 0, stream>>>(edges, E, hist, NBUCK);
    scanB_k<<<1, TBLOCK, 0, stream>>>(hist, base, cursor, NBUCK);
    scatterA_k<<<BUILD_GRID, TBLOCK, 0, stream>>>(edges, E, cursor, packed, NBUCK);
    buildB_k<<<NBUCK, TBLOCK, 0, stream>>>(packed, base, offs, degi, invdeg, csr, N);

    const int n8 = N * 128 / 8;
    const int nxb = (n8 + TBLOCK - 1) / TBLOCK;
    prep_k<<<nxb + 192, TBLOCK, 0, stream>>>(x, W1l, W1r, W2l, W2r, xb, wc1, wc2, n8, nxb);

    // layer 1: agg1b = bf16(mean_agg(xb))
    gatherb_k<128, false><<<(N + 15) / 16, TBLOCK, 0, stream>>>(
        xb, csr, offs, degi, invdeg, agg1b, nullptr, N);
    // hb = bf16(relu([agg1b | xb] @ [W1l; W1r] + b1))
    gemm_k<256, 1><<<(N + 127) / 128, TBLOCK, 0, stream>>>(
        agg1b, xb, wc1, b1, hb, nullptr, N);

    // layer 2: t2b = bf16(hb @ W2l); out = hb @ W2r + b2
    gemm_k<128, 2><<<(N + 127) / 128, TBLOCK, 0, stream>>>(
        hb, nullptr, wc2, b2, t2b, out, N);
    // out += mean_agg(t2b)
    gatherb_k<64, true><<<(N + 31) / 32, TBLOCK, 0, stream>>>(
        t2b, csr, offs, degi, invdeg, nullptr, out, N);
}